// Round 9
// baseline (812.783 us; speedup 1.0000x reference)
//
#include <hip/hip_runtime.h>
#include <stdint.h>
#include <stddef.h>

// ---------------------------------------------------------------------------
// Neural SDE: B=2048 paths, 64 Euler-Maruyama steps.
// R9: R8 structure (128 self-contained WGs, BB=16, 1024 thr = 16 waves ->
// 4 waves/SIMD, L1/L2 path-split). Two fixes:
//  (1) NAMED register double-buffer for the Wc2 stream (bA0..3/bB0..3) and
//      named A-frags -- R6/R7/R8's indexed ring arrays were demoted to
//      scratch (WRITE_SIZE 8-34MB vs 4.2MB out; VGPR_Count 64), putting
//      ~900-cyc scratch chains in the hot loop. Nothing indexable remains.
//  (2) Readout rebalanced across all 16 waves (wave=row, lane=(dd,kchunk),
//      8 fma + 3-stage DPP reduce) -- removes waves 0-1's ~600cyc serial
//      tail at every B1 convergence.
// Math identical to R8 (absmax 1.0625 proven).
// ---------------------------------------------------------------------------

typedef __attribute__((ext_vector_type(8))) short bf16x8;   // 8 x bf16 (4 VGPR)
typedef __attribute__((ext_vector_type(4))) float f32x4;    // MFMA C/D
typedef __attribute__((ext_vector_type(4))) int   i32x4;    // 16B copies

#define BB 16
#define NWG 128

// ---- ws layout (bytes), all bf16 fragment-swizzled weights --------------
#define WS_WI0 0        // 8 frags   (128x32  K=32  KI=1 NT=8)
#define WS_WI1 8192     // 32 frags  (128x128)
#define WS_WI2 40960    // 16 frags  (64x128)
#define WS_WV0 57344    // 16 frags  (128x64, t-col dropped)
#define WS_WV1 73728    // 32 frags
#define WS_WV2 106496   // 16 frags
#define WS_WC0 122880   // 16 frags
#define WS_WC1 139264   // 32 frags
#define WS_WC2 172032   // 512 frags (2048x128) = 512 KB
#define WS_TV0 696320   // Wv0[:,0] f32 [128]
#define WS_TC0 696832   // Wc0[:,0] f32 [128]

// ---- LDS layout (bytes) --------------------------------------------------
#define LD_WV0 0        // 16384
#define LD_WV1 16384    // 32768
#define LD_WC0 49152    // 16384
#define LD_WC1 65536    // 32768
#define LD_YBF 98304    // 2048: y A-frags K=64
#define LD_H1V 100352   // 4096
#define LD_H1C 104448   // 4096
#define LD_H2V 108544   // 4096
#define LD_H2C 112640   // 4096
#define LD_Y   116736   // f32 [16][68] = 4352 (stride 68: 16B-aligned rows)
#define LD_DB  121088   // f32 [16][68]
#define LD_BM  125440   // f32 [16][33] = 2112
#define LD_BSC 127552   // u32 [2048]: bc2(bf16) | scale_c(bf16)<<16 per col
#define LD_BEV 135744   // f32 [128]
#define LD_BEC 136256
#define LD_BV1 136768
#define LD_BC1 137280
#define LD_BV2 137792   // f32 [64]
#define LD_SV  138048
#define LD_WR  138304   // f32 [8][68] = 2176
#define LD_BR  140480   // 32
#define LDS_TOTAL 140512   // >80KB => 1 WG/CU; 16 waves => 4 waves/SIMD

__device__ __forceinline__ short f2bf(float f) {
  uint32_t u = __builtin_bit_cast(uint32_t, f);
  uint32_t r = (u + 0x7fffu + ((u >> 16) & 1u)) >> 16;   // RNE
  return (short)r;
}
__device__ __forceinline__ float bf2f(short s) {
  uint32_t u = ((uint32_t)(uint16_t)s) << 16;
  return __builtin_bit_cast(float, u);
}
// R6-proven form (absmax 1.0625): clamp keeps (e-1)*rcp(e+1) NaN-free.
__device__ __forceinline__ float tanh_fast(float x) {
  x = fminf(15.f, fmaxf(-15.f, x));
  float e = __builtin_amdgcn_exp2f(x * 2.8853900817779268f); // 2*log2(e)
  return (e - 1.f) * __builtin_amdgcn_rcpf(e + 1.f);
}
__device__ __forceinline__ float lipswish(float x) {
  float s = __builtin_amdgcn_rcpf(1.f + __builtin_amdgcn_exp2f(-1.4426950408889634f * x));
  return 0.909f * x * s;
}
__device__ __forceinline__ float red16(float x) {
  int v;
  v = __builtin_amdgcn_update_dpp(0, __builtin_bit_cast(int, x), 0xB1, 0xF, 0xF, true);
  x += __builtin_bit_cast(float, v);
  v = __builtin_amdgcn_update_dpp(0, __builtin_bit_cast(int, x), 0x4E, 0xF, 0xF, true);
  x += __builtin_bit_cast(float, v);
  v = __builtin_amdgcn_update_dpp(0, __builtin_bit_cast(int, x), 0x141, 0xF, 0xF, true);
  x += __builtin_bit_cast(float, v);
  v = __builtin_amdgcn_update_dpp(0, __builtin_bit_cast(int, x), 0x140, 0xF, 0xF, true);
  x += __builtin_bit_cast(float, v);
  return x;
}
// sum over 8-lane group (lanes grouped by lane>>3), result in all 8
__device__ __forceinline__ float red8(float x) {
  int v;
  v = __builtin_amdgcn_update_dpp(0, __builtin_bit_cast(int, x), 0xB1, 0xF, 0xF, true);
  x += __builtin_bit_cast(float, v);
  v = __builtin_amdgcn_update_dpp(0, __builtin_bit_cast(int, x), 0x4E, 0xF, 0xF, true);
  x += __builtin_bit_cast(float, v);
  v = __builtin_amdgcn_update_dpp(0, __builtin_bit_cast(int, x), 0x141, 0xF, 0xF, true);
  x += __builtin_bit_cast(float, v);
  return x;
}
// write activation element (m,k) into a fragment-swizzled bf16 A-buffer
__device__ __forceinline__ void write_act(char* buf, int m, int k, short v) {
  int addr = ((k >> 5) << 10) + (m + ((k >> 3) & 3) * 16) * 16 + ((k & 7) << 1);
  *(short*)(buf + addr) = v;
}

template<int KF>
__device__ __forceinline__ f32x4 gemm_tile(const char* abase, const char* bbase, int lane) {
  f32x4 acc = {0.f, 0.f, 0.f, 0.f};
#pragma unroll
  for (int k = 0; k < KF; k++) {
    bf16x8 a = *(const bf16x8*)(abase + k * 1024 + lane * 16);
    bf16x8 b = *(const bf16x8*)(bbase + k * 1024 + lane * 16);
    acc = __builtin_amdgcn_mfma_f32_16x16x32_bf16(a, b, acc, 0, 0, 0);
  }
  return acc;
}

// ---------------------------------------------------------------------------
// Prep: f32 weights -> bf16 fragment-swizzled blobs in ws. (unchanged)
// ---------------------------------------------------------------------------
__global__ __launch_bounds__(256) void prep_kernel(
    const float* Wi0, const float* Wi1, const float* Wi2,
    const float* Wv0, const float* Wv1, const float* Wv2,
    const float* Wc0, const float* Wc1, const float* Wc2, char* ws) {
  int gid = blockIdx.x * 256 + threadIdx.x;
  if (gid < 680 * 64) {
    int frag = gid >> 6, lane = gid & 63;
    const float* src; int start, KI, srcK, c0;
    if      (frag < 8)   { src = Wi0; start = 0;   KI = 1; srcK = 32;  c0 = 0; }
    else if (frag < 40)  { src = Wi1; start = 8;   KI = 4; srcK = 128; c0 = 0; }
    else if (frag < 56)  { src = Wi2; start = 40;  KI = 4; srcK = 128; c0 = 0; }
    else if (frag < 72)  { src = Wv0; start = 56;  KI = 2; srcK = 65;  c0 = 1; }
    else if (frag < 104) { src = Wv1; start = 72;  KI = 4; srcK = 128; c0 = 0; }
    else if (frag < 120) { src = Wv2; start = 104; KI = 4; srcK = 128; c0 = 0; }
    else if (frag < 136) { src = Wc0; start = 120; KI = 2; srcK = 65;  c0 = 1; }
    else if (frag < 168) { src = Wc1; start = 136; KI = 4; srcK = 128; c0 = 0; }
    else                 { src = Wc2; start = 168; KI = 4; srcK = 128; c0 = 0; }
    int rel = frag - start;
    int nt = rel / KI, ki = rel % KI;
    int n16 = lane & 15, quad = lane >> 4;
    const float* s = src + (nt * 16 + n16) * srcK + c0 + ki * 32 + quad * 8;
    bf16x8 v;
#pragma unroll
    for (int j = 0; j < 8; j++) v[j] = f2bf(s[j]);
    *(bf16x8*)(ws + (size_t)frag * 1024 + lane * 16) = v;
  } else {
    int i = gid - 680 * 64;
    if (i < 128)      ((float*)(ws + WS_TV0))[i] = Wv0[i * 65];
    else if (i < 256) ((float*)(ws + WS_TC0))[i - 128] = Wc0[(i - 128) * 65];
  }
}

// ---------------------------------------------------------------------------
// Main persistent kernel: one WG = 16 batch rows, 16 waves, all 64 steps.
// ---------------------------------------------------------------------------
__global__ __launch_bounds__(1024, 4)
void sde_kernel(
    const float* ts, const float* init_noise, const float* bm,
    const float* bi0, const float* bi1, const float* bi2,
    const float* bv0, const float* bv1, const float* bv2, const float* scale_v,
    const float* bc0, const float* bc1, const float* bc2, const float* scale_c,
    const float* Wr, const float* br,
    const char* ws, float* out) {
  extern __shared__ __align__(16) char lds[];
  const int tid  = threadIdx.x;
  const int lane = tid & 63;
  const int wv   = tid >> 6;     // wave 0..15
  const int nl   = lane & 15;
  const int quad = lane >> 4;
  const int b0   = blockIdx.x * BB;
  const int w8   = wv & 7;       // wave-within-path
  const int path = wv >> 3;      // 0: v-path, 1: c-path (L1/L2)
  const char* wc2 = ws + WS_WC2 + (size_t)(wv * 8) * 4096;  // this wave's 8 tiles

  // ---- persistent per-thread effective-bias source regs (tids 512..767) ----
  float tvq = 0.f, bbq = 0.f;
  if (tid >= 512 && tid < 768) {
    int j = tid - 512;
    if (j < 128) { tvq = ((const float*)(ws + WS_TV0))[j];       bbq = bv0[j]; }
    else         { tvq = ((const float*)(ws + WS_TC0))[j - 128]; bbq = bc0[j - 128]; }
  }

  // ---- stage small weights & params into LDS ----
  {
    const i32x4* s0 = (const i32x4*)(ws + WS_WV0);   // WV0+WV1 = 49152 B
    const i32x4* s1 = (const i32x4*)(ws + WS_WC0);   // WC0+WC1 = 49152 B
    i32x4* d0 = (i32x4*)(lds + LD_WV0);
    i32x4* d1 = (i32x4*)(lds + LD_WC0);
    for (int j = tid; j < 3072; j += 1024) { d0[j] = s0[j]; d1[j] = s1[j]; }
  }
  for (int j = tid; j < 2048; j += 1024) {   // packed bc2|scale_c per col
    uint32_t u = (uint32_t)(uint16_t)f2bf(bc2[j]) |
                 ((uint32_t)(uint16_t)f2bf(scale_c[j]) << 16);
    ((uint32_t*)(lds + LD_BSC))[j] = u;
  }
  if (tid < 128)      { ((float*)(lds + LD_BV1))[tid] = bv1[tid];
                        ((float*)(lds + LD_BC1))[tid] = bc1[tid]; }
  else if (tid < 192) { int k = tid - 128; ((float*)(lds + LD_BV2))[k] = bv2[k];
                        ((float*)(lds + LD_SV))[k] = scale_v[k]; }
  else if (tid < 200) { int k = tid - 192; ((float*)(lds + LD_BR))[k] = br[k]; }
  if (tid < 512) { int dd = tid >> 6, k = tid & 63;
    ((float*)(lds + LD_WR))[dd * 68 + k] = Wr[dd * 64 + k]; }
  // init noise -> YBF (K=32)
  if (tid < 512) { int m = tid >> 5, k = tid & 31;
    write_act(lds + LD_YBF, m, k, f2bf(init_noise[(b0 + m) * 32 + k])); }
  __syncthreads();

  // ---- init MLP: noise -> y0 (waves 0-7 work; others idle through barriers) --
  if (wv < 8) {
    f32x4 acc = gemm_tile<1>(lds + LD_YBF, ws + WS_WI0 + wv * 1024, lane);
    int col = wv * 16 + nl; float bias = bi0[col];
#pragma unroll
    for (int r = 0; r < 4; r++)
      write_act(lds + LD_H1V, quad * 4 + r, col, f2bf(fmaxf(0.f, acc[r] + bias)));
  }
  __syncthreads();
  if (wv < 8) {
    f32x4 acc = gemm_tile<4>(lds + LD_H1V, ws + WS_WI1 + wv * 4096, lane);
    int col = wv * 16 + nl; float bias = bi1[col];
#pragma unroll
    for (int r = 0; r < 4; r++)
      write_act(lds + LD_H2V, quad * 4 + r, col, f2bf(fmaxf(0.f, acc[r] + bias)));
  }
  __syncthreads();
  if (wv < 4) {
    f32x4 acc = gemm_tile<4>(lds + LD_H2V, ws + WS_WI2 + wv * 4096, lane);
    int col = wv * 16 + nl; float bias = bi2[col];
#pragma unroll
    for (int r = 0; r < 4; r++)
      ((float*)(lds + LD_Y))[(quad * 4 + r) * 68 + col] = acc[r] + bias;
  }
  __syncthreads();

  // ---- preamble: YBF from Y; bm step0; effective biases step0 ----
  const float ts0 = ts[0];
  { int row = tid >> 6, k = tid & 63;
    write_act(lds + LD_YBF, row, k, f2bf(((float*)(lds + LD_Y))[row * 68 + k])); }
  if (tid < 512)
    ((float*)(lds + LD_BM))[(tid >> 5) * 33 + (tid & 31)] =
        bm[((size_t)(b0 + (tid >> 5)) * 64 + 0) * 32 + (tid & 31)];
  if (tid >= 512 && tid < 768) {
    int j = tid - 512; float v = bbq + ts0 * tvq;
    if (j < 128) ((float*)(lds + LD_BEV))[j] = v;
    else         ((float*)(lds + LD_BEC))[j - 128] = v;
  }
  __syncthreads();

  // ================= 64-step scan =================
  for (int step = 0; step < 64; step++) {
    // ---- step-top prefetch: next bm; preload Wc2 tiles 0,1 (named regs) ----
    float bm_next = 0.f;
    if (tid < 512 && step + 1 < 64)
      bm_next = bm[((size_t)(b0 + (tid >> 5)) * 64 + (step + 1)) * 32 + (tid & 31)];
    bf16x8 bA0 = *(const bf16x8*)(wc2 +    0 + lane * 16);
    bf16x8 bA1 = *(const bf16x8*)(wc2 + 1024 + lane * 16);
    bf16x8 bA2 = *(const bf16x8*)(wc2 + 2048 + lane * 16);
    bf16x8 bA3 = *(const bf16x8*)(wc2 + 3072 + lane * 16);
    bf16x8 bB0 = *(const bf16x8*)(wc2 + 4096 +    0 + lane * 16);
    bf16x8 bB1 = *(const bf16x8*)(wc2 + 4096 + 1024 + lane * 16);
    bf16x8 bB2 = *(const bf16x8*)(wc2 + 4096 + 2048 + lane * 16);
    bf16x8 bB3 = *(const bf16x8*)(wc2 + 4096 + 3072 + lane * 16);

    // ---- L1: waves 0-7 v-path, waves 8-15 c-path ----
    {
      int col = w8 * 16 + nl;
      const char* wgt = lds + (path ? LD_WC0 : LD_WV0) + w8 * 2048;
      char* h1 = lds + (path ? LD_H1C : LD_H1V);
      float be = ((const float*)(lds + (path ? LD_BEC : LD_BEV)))[col];
      f32x4 acc = gemm_tile<2>(lds + LD_YBF, wgt, lane);
#pragma unroll
      for (int r = 0; r < 4; r++)
        write_act(h1, quad * 4 + r, col, f2bf(lipswish(acc[r] + be)));
    }
    __syncthreads();   // B1
    // ---- L2 ----
    {
      int col = w8 * 16 + nl;
      const char* h1 = lds + (path ? LD_H1C : LD_H1V);
      const char* wgt = lds + (path ? LD_WC1 : LD_WV1) + w8 * 4096;
      char* h2 = lds + (path ? LD_H2C : LD_H2V);
      float be = ((const float*)(lds + (path ? LD_BC1 : LD_BV1)))[col];
      f32x4 acc = gemm_tile<4>(h1, wgt, lane);
#pragma unroll
      for (int r = 0; r < 4; r++)
        write_act(h2, quad * 4 + r, col, f2bf(lipswish(acc[r] + be)));
    }
    __syncthreads();   // B2
    // ---- L3: drift (waves 0-3) + diffusion (all waves) ----
    if (wv < 4) {
      f32x4 acc = gemm_tile<4>(lds + LD_H2V, ws + WS_WV2 + wv * 4096, lane);
      int col = wv * 16 + nl;
      float bias = ((float*)(lds + LD_BV2))[col];
      float sv   = ((float*)(lds + LD_SV))[col];
#pragma unroll
      for (int r = 0; r < 4; r++)
        ((float*)(lds + LD_DB))[(quad * 4 + r) * 68 + col] = sv * tanh_fast(acc[r] + bias);
    }
    {
      bf16x8 a0f = *(const bf16x8*)(lds + LD_H2C +    0 + lane * 16);
      bf16x8 a1f = *(const bf16x8*)(lds + LD_H2C + 1024 + lane * 16);
      bf16x8 a2f = *(const bf16x8*)(lds + LD_H2C + 2048 + lane * 16);
      bf16x8 a3f = *(const bf16x8*)(lds + LD_H2C + 3072 + lane * 16);
      const float* bmp = (const float*)(lds + LD_BM);
      float bmr00 = bmp[(quad * 4 + 0) * 33 + nl];
      float bmr01 = bmp[(quad * 4 + 1) * 33 + nl];
      float bmr02 = bmp[(quad * 4 + 2) * 33 + nl];
      float bmr03 = bmp[(quad * 4 + 3) * 33 + nl];
      float bmr10 = bmp[(quad * 4 + 0) * 33 + 16 + nl];
      float bmr11 = bmp[(quad * 4 + 1) * 33 + 16 + nl];
      float bmr12 = bmp[(quad * 4 + 2) * 33 + 16 + nl];
      float bmr13 = bmp[(quad * 4 + 3) * 33 + 16 + nl];
      float ps0, ps1, ps2, ps3;

#define DIFF_PAIR(P)                                                          \
      {  /* even tile tt=2P, slot A */                                        \
        f32x4 acc = {0.f, 0.f, 0.f, 0.f};                                     \
        acc = __builtin_amdgcn_mfma_f32_16x16x32_bf16(a0f, bA0, acc, 0, 0, 0);\
        acc = __builtin_amdgcn_mfma_f32_16x16x32_bf16(a1f, bA1, acc, 0, 0, 0);\
        acc = __builtin_amdgcn_mfma_f32_16x16x32_bf16(a2f, bA2, acc, 0, 0, 0);\
        acc = __builtin_amdgcn_mfma_f32_16x16x32_bf16(a3f, bA3, acc, 0, 0, 0);\
        if ((P) < 3) {                                                        \
          bA0 = *(const bf16x8*)(wc2 + (2*(P)+2)*4096 +    0 + lane*16);      \
          bA1 = *(const bf16x8*)(wc2 + (2*(P)+2)*4096 + 1024 + lane*16);      \
          bA2 = *(const bf16x8*)(wc2 + (2*(P)+2)*4096 + 2048 + lane*16);      \
          bA3 = *(const bf16x8*)(wc2 + (2*(P)+2)*4096 + 3072 + lane*16);      \
        }                                                                     \
        uint32_t bsc = ((const uint32_t*)(lds + LD_BSC))[(wv*8 + 2*(P))*16 + nl];\
        float bc2v = bf2f((short)(bsc & 0xffffu));                            \
        float scv  = bf2f((short)(bsc >> 16));                                \
        ps0 = tanh_fast(acc[0] + bc2v) * scv * bmr00;                         \
        ps1 = tanh_fast(acc[1] + bc2v) * scv * bmr01;                         \
        ps2 = tanh_fast(acc[2] + bc2v) * scv * bmr02;                         \
        ps3 = tanh_fast(acc[3] + bc2v) * scv * bmr03;                         \
      }                                                                       \
      {  /* odd tile tt=2P+1, slot B */                                       \
        f32x4 acc = {0.f, 0.f, 0.f, 0.f};                                     \
        acc = __builtin_amdgcn_mfma_f32_16x16x32_bf16(a0f, bB0, acc, 0, 0, 0);\
        acc = __builtin_amdgcn_mfma_f32_16x16x32_bf16(a1f, bB1, acc, 0, 0, 0);\
        acc = __builtin_amdgcn_mfma_f32_16x16x32_bf16(a2f, bB2, acc, 0, 0, 0);\
        acc = __builtin_amdgcn_mfma_f32_16x16x32_bf16(a3f, bB3, acc, 0, 0, 0);\
        if ((P) < 3) {                                                        \
          bB0 = *(const bf16x8*)(wc2 + (2*(P)+3)*4096 +    0 + lane*16);      \
          bB1 = *(const bf16x8*)(wc2 + (2*(P)+3)*4096 + 1024 + lane*16);      \
          bB2 = *(const bf16x8*)(wc2 + (2*(P)+3)*4096 + 2048 + lane*16);      \
          bB3 = *(const bf16x8*)(wc2 + (2*(P)+3)*4096 + 3072 + lane*16);      \
        }                                                                     \
        uint32_t bsc = ((const uint32_t*)(lds + LD_BSC))[(wv*8 + 2*(P)+1)*16 + nl];\
        float bc2v = bf2f((short)(bsc & 0xffffu));                            \
        float scv  = bf2f((short)(bsc >> 16));                                \
        ps0 += tanh_fast(acc[0] + bc2v) * scv * bmr10;                        \
        ps1 += tanh_fast(acc[1] + bc2v) * scv * bmr11;                        \
        ps2 += tanh_fast(acc[2] + bc2v) * scv * bmr12;                        \
        ps3 += tanh_fast(acc[3] + bc2v) * scv * bmr13;                        \
        ps0 = red16(ps0); ps1 = red16(ps1); ps2 = red16(ps2); ps3 = red16(ps3);\
        if (nl < 4) {                                                         \
          int row = quad * 4 + nl;                                            \
          float s = (nl == 0) ? ps0 : (nl == 1) ? ps1 : (nl == 2) ? ps2 : ps3;\
          ((float*)(lds + LD_Y))[row * 68 + (wv * 4 + (P))] += s;             \
        }                                                                     \
      }

      DIFF_PAIR(0)
      DIFF_PAIR(1)
      DIFF_PAIR(2)
      DIFF_PAIR(3)
#undef DIFF_PAIR
    }
    __syncthreads();   // B3
    // ---- M: vnew = Y(+diff) + DB; rebuild YBF; stage bm/biases ----
    {
      int row = tid >> 6, k = tid & 63;
      float vn = ((float*)(lds + LD_Y))[row * 68 + k] +
                 ((float*)(lds + LD_DB))[row * 68 + k];
      ((float*)(lds + LD_Y))[row * 68 + k] = vn;
      write_act(lds + LD_YBF, row, k, f2bf(vn));
    }
    if (step + 1 < 64) {
      if (tid < 512)
        ((float*)(lds + LD_BM))[(tid >> 5) * 33 + (tid & 31)] = bm_next;
      else if (tid < 768) {
        int j = tid - 512; float v = bbq + (ts0 + (float)(step + 1)) * tvq;
        if (j < 128) ((float*)(lds + LD_BEV))[j] = v;
        else         ((float*)(lds + LD_BEC))[j - 128] = v;
      }
    }
    __syncthreads();   // B4
    // ---- readout: wave wv = row wv; lane = (dd = lane>>3, kchunk = lane&7) --
    {
      int dd = lane >> 3, kg = lane & 7;
      const float* yr = (const float*)(lds + LD_Y) + wv * 68;
      const float* wr = (const float*)(lds + LD_WR) + dd * 68;
      float s = 0.f;
#pragma unroll
      for (int i = 0; i < 8; i++) s = fmaf(yr[kg + 8 * i], wr[kg + 8 * i], s);
      s = red8(s);
      if (kg == 0)
        out[(size_t)(b0 + wv) * 512 + step * 8 + dd] =
            s + ((const float*)(lds + LD_BR))[dd];
    }
  }
}

extern "C" void kernel_launch(void* const* d_in, const int* in_sizes, int n_in,
                              void* d_out, int out_size, void* d_ws, size_t ws_size,
                              hipStream_t stream) {
  (void)in_sizes; (void)n_in; (void)out_size; (void)ws_size;
  const float* ts         = (const float*)d_in[0];
  const float* init_noise = (const float*)d_in[1];
  const float* bm         = (const float*)d_in[2];
  const float* Wi0 = (const float*)d_in[3];
  const float* bi0 = (const float*)d_in[4];
  const float* Wi1 = (const float*)d_in[5];
  const float* bi1 = (const float*)d_in[6];
  const float* Wi2 = (const float*)d_in[7];
  const float* bi2 = (const float*)d_in[8];
  const float* scale_v = (const float*)d_in[9];
  const float* Wv0 = (const float*)d_in[10];
  const float* bv0 = (const float*)d_in[11];
  const float* Wv1 = (const float*)d_in[12];
  const float* bv1 = (const float*)d_in[13];
  const float* Wv2 = (const float*)d_in[14];
  const float* bv2 = (const float*)d_in[15];
  const float* scale_c = (const float*)d_in[16];
  const float* Wc0 = (const float*)d_in[17];
  const float* bc0 = (const float*)d_in[18];
  const float* Wc1 = (const float*)d_in[19];
  const float* bc1 = (const float*)d_in[20];
  const float* Wc2 = (const float*)d_in[21];
  const float* bc2 = (const float*)d_in[22];
  const float* Wr  = (const float*)d_in[23];
  const float* br  = (const float*)d_in[24];
  char*  ws  = (char*)d_ws;
  float* out = (float*)d_out;

  hipFuncSetAttribute((const void*)sde_kernel,
                      hipFuncAttributeMaxDynamicSharedMemorySize, LDS_TOTAL);

  prep_kernel<<<171, 256, 0, stream>>>(Wi0, Wi1, Wi2, Wv0, Wv1, Wv2, Wc0, Wc1, Wc2, ws);
  sde_kernel<<<NWG, 1024, LDS_TOTAL, stream>>>(
      ts, init_noise, bm, bi0, bi1, bi2, bv0, bv1, bv2, scale_v,
      bc0, bc1, bc2, scale_c, Wr, br, ws, out);
}

// Round 10
// 726.707 us; speedup vs baseline: 1.1184x; 1.1184x over previous
//
#include <hip/hip_runtime.h>
#include <stdint.h>
#include <stddef.h>

// ---------------------------------------------------------------------------
// Neural SDE: B=2048 paths, 64 Euler-Maruyama steps.
// R10: 128 self-contained WGs, BB=16, 1024 thr = 16 waves -> 4 waves/SIMD.
// 1024-thr blocks empirically cap arch-VGPRs at 64 (R7/R8/R9 all spilled);
// this round fits the hot loop in 64:
//  - NO across-barrier Wc2 prefetch (R9 held 32 VGPRs live across B1+B2 on
//    top of the L1/L2 temporaries -- the actual spill cause). B-frag loads
//    issue after B2, hidden behind the drift MFMAs.
//  - bm/bsc read transiently from LDS inside the epilogue (no residency).
//  - drift weights WV2 staged to LDS (153KB total) -- no per-step global
//    latency chain in the drift phase.
// Math identical to R8/R9 (absmax 1.0625 proven).
// ---------------------------------------------------------------------------

typedef __attribute__((ext_vector_type(8))) short bf16x8;   // 8 x bf16 (4 VGPR)
typedef __attribute__((ext_vector_type(4))) float f32x4;    // MFMA C/D
typedef __attribute__((ext_vector_type(4))) int   i32x4;    // 16B copies

#define BB 16
#define NWG 128

// ---- ws layout (bytes), all bf16 fragment-swizzled weights --------------
#define WS_WI0 0        // 8 frags   (128x32  K=32  KI=1 NT=8)
#define WS_WI1 8192     // 32 frags  (128x128)
#define WS_WI2 40960    // 16 frags  (64x128)
#define WS_WV0 57344    // 16 frags  (128x64, t-col dropped)
#define WS_WV1 73728    // 32 frags
#define WS_WV2 106496   // 16 frags
#define WS_WC0 122880   // 16 frags
#define WS_WC1 139264   // 32 frags
#define WS_WC2 172032   // 512 frags (2048x128) = 512 KB
#define WS_TV0 696320   // Wv0[:,0] f32 [128]
#define WS_TC0 696832   // Wc0[:,0] f32 [128]

// ---- LDS layout (bytes) --------------------------------------------------
#define LD_WV0 0        // 16384
#define LD_WV1 16384    // 32768
#define LD_WC0 49152    // 16384
#define LD_WC1 65536    // 32768
#define LD_YBF 98304    // 2048: y A-frags K=64
#define LD_H1V 100352   // 4096
#define LD_H1C 104448   // 4096
#define LD_H2V 108544   // 4096
#define LD_H2C 112640   // 4096
#define LD_Y   116736   // f32 [16][68] = 4352 (stride 68: 16B-aligned rows)
#define LD_DB  121088   // f32 [16][68]
#define LD_BM  125440   // f32 [16][33] = 2112
#define LD_BSC 127552   // u32 [2048]: bc2(bf16) | scale_c(bf16)<<16 per col
#define LD_BEV 135744   // f32 [128]
#define LD_BEC 136256
#define LD_BV1 136768
#define LD_BC1 137280
#define LD_BV2 137792   // f32 [64]
#define LD_SV  138048
#define LD_WR  138304   // f32 [8][68] = 2176
#define LD_BR  140480   // 32
#define LD_WV2F 140512  // 16384: drift L3 weight frags (staged from ws)
#define LDS_TOTAL 156896   // <160KB HW; >80KB => 1 WG/CU => 4 waves/SIMD

__device__ __forceinline__ short f2bf(float f) {
  uint32_t u = __builtin_bit_cast(uint32_t, f);
  uint32_t r = (u + 0x7fffu + ((u >> 16) & 1u)) >> 16;   // RNE
  return (short)r;
}
__device__ __forceinline__ float bf2f(short s) {
  uint32_t u = ((uint32_t)(uint16_t)s) << 16;
  return __builtin_bit_cast(float, u);
}
// R6-proven form (absmax 1.0625): clamp keeps (e-1)*rcp(e+1) NaN-free.
__device__ __forceinline__ float tanh_fast(float x) {
  x = fminf(15.f, fmaxf(-15.f, x));
  float e = __builtin_amdgcn_exp2f(x * 2.8853900817779268f); // 2*log2(e)
  return (e - 1.f) * __builtin_amdgcn_rcpf(e + 1.f);
}
__device__ __forceinline__ float lipswish(float x) {
  float s = __builtin_amdgcn_rcpf(1.f + __builtin_amdgcn_exp2f(-1.4426950408889634f * x));
  return 0.909f * x * s;
}
__device__ __forceinline__ float red16(float x) {
  int v;
  v = __builtin_amdgcn_update_dpp(0, __builtin_bit_cast(int, x), 0xB1, 0xF, 0xF, true);
  x += __builtin_bit_cast(float, v);
  v = __builtin_amdgcn_update_dpp(0, __builtin_bit_cast(int, x), 0x4E, 0xF, 0xF, true);
  x += __builtin_bit_cast(float, v);
  v = __builtin_amdgcn_update_dpp(0, __builtin_bit_cast(int, x), 0x141, 0xF, 0xF, true);
  x += __builtin_bit_cast(float, v);
  v = __builtin_amdgcn_update_dpp(0, __builtin_bit_cast(int, x), 0x140, 0xF, 0xF, true);
  x += __builtin_bit_cast(float, v);
  return x;
}
// sum over 8-lane group (lanes grouped by lane>>3), result in all 8
__device__ __forceinline__ float red8(float x) {
  int v;
  v = __builtin_amdgcn_update_dpp(0, __builtin_bit_cast(int, x), 0xB1, 0xF, 0xF, true);
  x += __builtin_bit_cast(float, v);
  v = __builtin_amdgcn_update_dpp(0, __builtin_bit_cast(int, x), 0x4E, 0xF, 0xF, true);
  x += __builtin_bit_cast(float, v);
  v = __builtin_amdgcn_update_dpp(0, __builtin_bit_cast(int, x), 0x141, 0xF, 0xF, true);
  x += __builtin_bit_cast(float, v);
  return x;
}
// write activation element (m,k) into a fragment-swizzled bf16 A-buffer
__device__ __forceinline__ void write_act(char* buf, int m, int k, short v) {
  int addr = ((k >> 5) << 10) + (m + ((k >> 3) & 3) * 16) * 16 + ((k & 7) << 1);
  *(short*)(buf + addr) = v;
}

template<int KF>
__device__ __forceinline__ f32x4 gemm_tile(const char* abase, const char* bbase, int lane) {
  f32x4 acc = {0.f, 0.f, 0.f, 0.f};
#pragma unroll
  for (int k = 0; k < KF; k++) {
    bf16x8 a = *(const bf16x8*)(abase + k * 1024 + lane * 16);
    bf16x8 b = *(const bf16x8*)(bbase + k * 1024 + lane * 16);
    acc = __builtin_amdgcn_mfma_f32_16x16x32_bf16(a, b, acc, 0, 0, 0);
  }
  return acc;
}

// ---------------------------------------------------------------------------
// Prep: f32 weights -> bf16 fragment-swizzled blobs in ws. (unchanged)
// ---------------------------------------------------------------------------
__global__ __launch_bounds__(256) void prep_kernel(
    const float* Wi0, const float* Wi1, const float* Wi2,
    const float* Wv0, const float* Wv1, const float* Wv2,
    const float* Wc0, const float* Wc1, const float* Wc2, char* ws) {
  int gid = blockIdx.x * 256 + threadIdx.x;
  if (gid < 680 * 64) {
    int frag = gid >> 6, lane = gid & 63;
    const float* src; int start, KI, srcK, c0;
    if      (frag < 8)   { src = Wi0; start = 0;   KI = 1; srcK = 32;  c0 = 0; }
    else if (frag < 40)  { src = Wi1; start = 8;   KI = 4; srcK = 128; c0 = 0; }
    else if (frag < 56)  { src = Wi2; start = 40;  KI = 4; srcK = 128; c0 = 0; }
    else if (frag < 72)  { src = Wv0; start = 56;  KI = 2; srcK = 65;  c0 = 1; }
    else if (frag < 104) { src = Wv1; start = 72;  KI = 4; srcK = 128; c0 = 0; }
    else if (frag < 120) { src = Wv2; start = 104; KI = 4; srcK = 128; c0 = 0; }
    else if (frag < 136) { src = Wc0; start = 120; KI = 2; srcK = 65;  c0 = 1; }
    else if (frag < 168) { src = Wc1; start = 136; KI = 4; srcK = 128; c0 = 0; }
    else                 { src = Wc2; start = 168; KI = 4; srcK = 128; c0 = 0; }
    int rel = frag - start;
    int nt = rel / KI, ki = rel % KI;
    int n16 = lane & 15, quad = lane >> 4;
    const float* s = src + (nt * 16 + n16) * srcK + c0 + ki * 32 + quad * 8;
    bf16x8 v;
#pragma unroll
    for (int j = 0; j < 8; j++) v[j] = f2bf(s[j]);
    *(bf16x8*)(ws + (size_t)frag * 1024 + lane * 16) = v;
  } else {
    int i = gid - 680 * 64;
    if (i < 128)      ((float*)(ws + WS_TV0))[i] = Wv0[i * 65];
    else if (i < 256) ((float*)(ws + WS_TC0))[i - 128] = Wc0[(i - 128) * 65];
  }
}

// ---------------------------------------------------------------------------
// Main persistent kernel: one WG = 16 batch rows, 16 waves, all 64 steps.
// ---------------------------------------------------------------------------
__global__ __launch_bounds__(1024, 4)
void sde_kernel(
    const float* ts, const float* init_noise, const float* bm,
    const float* bi0, const float* bi1, const float* bi2,
    const float* bv0, const float* bv1, const float* bv2, const float* scale_v,
    const float* bc0, const float* bc1, const float* bc2, const float* scale_c,
    const float* Wr, const float* br,
    const char* ws, float* out) {
  extern __shared__ __align__(16) char lds[];
  const int tid  = threadIdx.x;
  const int lane = tid & 63;
  const int wv   = tid >> 6;     // wave 0..15
  const int nl   = lane & 15;
  const int quad = lane >> 4;
  const int b0   = blockIdx.x * BB;
  const int w8   = wv & 7;       // wave-within-path
  const int path = wv >> 3;      // 0: v-path, 1: c-path (L1/L2)
  const char* wc2 = ws + WS_WC2 + (size_t)(wv * 8) * 4096;  // this wave's 8 tiles

  // ---- persistent per-thread effective-bias source regs (tids 512..767) ----
  float tvq = 0.f, bbq = 0.f;
  if (tid >= 512 && tid < 768) {
    int j = tid - 512;
    if (j < 128) { tvq = ((const float*)(ws + WS_TV0))[j];       bbq = bv0[j]; }
    else         { tvq = ((const float*)(ws + WS_TC0))[j - 128]; bbq = bc0[j - 128]; }
  }

  // ---- stage small weights & params into LDS ----
  {
    const i32x4* s0 = (const i32x4*)(ws + WS_WV0);   // WV0+WV1 = 49152 B
    const i32x4* s1 = (const i32x4*)(ws + WS_WC0);   // WC0+WC1 = 49152 B
    i32x4* d0 = (i32x4*)(lds + LD_WV0);
    i32x4* d1 = (i32x4*)(lds + LD_WC0);
    for (int j = tid; j < 3072; j += 1024) { d0[j] = s0[j]; d1[j] = s1[j]; }
  }
  // drift L3 weight frags (16KB)
  ((i32x4*)(lds + LD_WV2F))[tid] = ((const i32x4*)(ws + WS_WV2))[tid];
  for (int j = tid; j < 2048; j += 1024) {   // packed bc2|scale_c per col
    uint32_t u = (uint32_t)(uint16_t)f2bf(bc2[j]) |
                 ((uint32_t)(uint16_t)f2bf(scale_c[j]) << 16);
    ((uint32_t*)(lds + LD_BSC))[j] = u;
  }
  if (tid < 128)      { ((float*)(lds + LD_BV1))[tid] = bv1[tid];
                        ((float*)(lds + LD_BC1))[tid] = bc1[tid]; }
  else if (tid < 192) { int k = tid - 128; ((float*)(lds + LD_BV2))[k] = bv2[k];
                        ((float*)(lds + LD_SV))[k] = scale_v[k]; }
  else if (tid < 200) { int k = tid - 192; ((float*)(lds + LD_BR))[k] = br[k]; }
  if (tid < 512) { int dd = tid >> 6, k = tid & 63;
    ((float*)(lds + LD_WR))[dd * 68 + k] = Wr[dd * 64 + k]; }
  // init noise -> YBF (K=32)
  if (tid < 512) { int m = tid >> 5, k = tid & 31;
    write_act(lds + LD_YBF, m, k, f2bf(init_noise[(b0 + m) * 32 + k])); }
  __syncthreads();

  // ---- init MLP: noise -> y0 (waves 0-7 work; others idle through barriers) --
  if (wv < 8) {
    f32x4 acc = gemm_tile<1>(lds + LD_YBF, ws + WS_WI0 + wv * 1024, lane);
    int col = wv * 16 + nl; float bias = bi0[col];
#pragma unroll
    for (int r = 0; r < 4; r++)
      write_act(lds + LD_H1V, quad * 4 + r, col, f2bf(fmaxf(0.f, acc[r] + bias)));
  }
  __syncthreads();
  if (wv < 8) {
    f32x4 acc = gemm_tile<4>(lds + LD_H1V, ws + WS_WI1 + wv * 4096, lane);
    int col = wv * 16 + nl; float bias = bi1[col];
#pragma unroll
    for (int r = 0; r < 4; r++)
      write_act(lds + LD_H2V, quad * 4 + r, col, f2bf(fmaxf(0.f, acc[r] + bias)));
  }
  __syncthreads();
  if (wv < 4) {
    f32x4 acc = gemm_tile<4>(lds + LD_H2V, ws + WS_WI2 + wv * 4096, lane);
    int col = wv * 16 + nl; float bias = bi2[col];
#pragma unroll
    for (int r = 0; r < 4; r++)
      ((float*)(lds + LD_Y))[(quad * 4 + r) * 68 + col] = acc[r] + bias;
  }
  __syncthreads();

  // ---- preamble: YBF from Y; bm step0; effective biases step0 ----
  const float ts0 = ts[0];
  { int row = tid >> 6, k = tid & 63;
    write_act(lds + LD_YBF, row, k, f2bf(((float*)(lds + LD_Y))[row * 68 + k])); }
  if (tid < 512)
    ((float*)(lds + LD_BM))[(tid >> 5) * 33 + (tid & 31)] =
        bm[((size_t)(b0 + (tid >> 5)) * 64 + 0) * 32 + (tid & 31)];
  if (tid >= 512 && tid < 768) {
    int j = tid - 512; float v = bbq + ts0 * tvq;
    if (j < 128) ((float*)(lds + LD_BEV))[j] = v;
    else         ((float*)(lds + LD_BEC))[j - 128] = v;
  }
  __syncthreads();

  // ================= 64-step scan =================
  for (int step = 0; step < 64; step++) {
    // ---- step-top prefetch: only next bm (1 VGPR live across phases) ----
    float bm_next = 0.f;
    if (tid < 512 && step + 1 < 64)
      bm_next = bm[((size_t)(b0 + (tid >> 5)) * 64 + (step + 1)) * 32 + (tid & 31)];

    // ---- L1: waves 0-7 v-path, waves 8-15 c-path ----
    {
      int col = w8 * 16 + nl;
      const char* wgt = lds + (path ? LD_WC0 : LD_WV0) + w8 * 2048;
      char* h1 = lds + (path ? LD_H1C : LD_H1V);
      float be = ((const float*)(lds + (path ? LD_BEC : LD_BEV)))[col];
      f32x4 acc = gemm_tile<2>(lds + LD_YBF, wgt, lane);
#pragma unroll
      for (int r = 0; r < 4; r++)
        write_act(h1, quad * 4 + r, col, f2bf(lipswish(acc[r] + be)));
    }
    __syncthreads();   // B1
    // ---- L2 ----
    {
      int col = w8 * 16 + nl;
      const char* h1 = lds + (path ? LD_H1C : LD_H1V);
      const char* wgt = lds + (path ? LD_WC1 : LD_WV1) + w8 * 4096;
      char* h2 = lds + (path ? LD_H2C : LD_H2V);
      float be = ((const float*)(lds + (path ? LD_BC1 : LD_BV1)))[col];
      f32x4 acc = gemm_tile<4>(h1, wgt, lane);
#pragma unroll
      for (int r = 0; r < 4; r++)
        write_act(h2, quad * 4 + r, col, f2bf(lipswish(acc[r] + be)));
    }
    __syncthreads();   // B2
    // ---- diffusion B-frag loads issue NOW (after B2, not across barriers);
    //      the drift MFMAs below overlap their L2 latency ----
    bf16x8 bE0 = *(const bf16x8*)(wc2 +    0 + lane * 16);
    bf16x8 bE1 = *(const bf16x8*)(wc2 + 1024 + lane * 16);
    bf16x8 bE2 = *(const bf16x8*)(wc2 + 2048 + lane * 16);
    bf16x8 bE3 = *(const bf16x8*)(wc2 + 3072 + lane * 16);
    bf16x8 bO0 = *(const bf16x8*)(wc2 + 4096 +    0 + lane * 16);
    bf16x8 bO1 = *(const bf16x8*)(wc2 + 4096 + 1024 + lane * 16);
    bf16x8 bO2 = *(const bf16x8*)(wc2 + 4096 + 2048 + lane * 16);
    bf16x8 bO3 = *(const bf16x8*)(wc2 + 4096 + 3072 + lane * 16);
    // ---- L3: drift (waves 0-3, weights from LDS) ----
    if (wv < 4) {
      f32x4 acc = gemm_tile<4>(lds + LD_H2V, lds + LD_WV2F + wv * 4096, lane);
      int col = wv * 16 + nl;
      float bias = ((float*)(lds + LD_BV2))[col];
      float sv   = ((float*)(lds + LD_SV))[col];
#pragma unroll
      for (int r = 0; r < 4; r++)
        ((float*)(lds + LD_DB))[(quad * 4 + r) * 68 + col] = sv * tanh_fast(acc[r] + bias);
    }
    // ---- diffusion: 4 pairs of tiles, double-buffered named B-frags ----
    {
      bf16x8 a0f = *(const bf16x8*)(lds + LD_H2C +    0 + lane * 16);
      bf16x8 a1f = *(const bf16x8*)(lds + LD_H2C + 1024 + lane * 16);
      bf16x8 a2f = *(const bf16x8*)(lds + LD_H2C + 2048 + lane * 16);
      bf16x8 a3f = *(const bf16x8*)(lds + LD_H2C + 3072 + lane * 16);
      const float* bmp = (const float*)(lds + LD_BM);
      const uint32_t* bscp = (const uint32_t*)(lds + LD_BSC) + wv * 128 + nl;
      float ps0, ps1, ps2, ps3;

#define DIFF_PAIR(P)                                                          \
      {  /* even tile 2P */                                                   \
        f32x4 acc = {0.f, 0.f, 0.f, 0.f};                                     \
        acc = __builtin_amdgcn_mfma_f32_16x16x32_bf16(a0f, bE0, acc, 0, 0, 0);\
        acc = __builtin_amdgcn_mfma_f32_16x16x32_bf16(a1f, bE1, acc, 0, 0, 0);\
        acc = __builtin_amdgcn_mfma_f32_16x16x32_bf16(a2f, bE2, acc, 0, 0, 0);\
        acc = __builtin_amdgcn_mfma_f32_16x16x32_bf16(a3f, bE3, acc, 0, 0, 0);\
        if ((P) < 3) {                                                        \
          bE0 = *(const bf16x8*)(wc2 + (2*(P)+2)*4096 +    0 + lane*16);      \
          bE1 = *(const bf16x8*)(wc2 + (2*(P)+2)*4096 + 1024 + lane*16);      \
          bE2 = *(const bf16x8*)(wc2 + (2*(P)+2)*4096 + 2048 + lane*16);      \
          bE3 = *(const bf16x8*)(wc2 + (2*(P)+2)*4096 + 3072 + lane*16);      \
        }                                                                     \
        uint32_t bsc = bscp[(2*(P))*16];                                      \
        float bc2v = bf2f((short)(bsc & 0xffffu));                            \
        float scv  = bf2f((short)(bsc >> 16));                                \
        ps0 = tanh_fast(acc[0] + bc2v) * scv * bmp[(quad*4+0)*33 + nl];       \
        ps1 = tanh_fast(acc[1] + bc2v) * scv * bmp[(quad*4+1)*33 + nl];       \
        ps2 = tanh_fast(acc[2] + bc2v) * scv * bmp[(quad*4+2)*33 + nl];       \
        ps3 = tanh_fast(acc[3] + bc2v) * scv * bmp[(quad*4+3)*33 + nl];       \
      }                                                                       \
      {  /* odd tile 2P+1 */                                                  \
        f32x4 acc = {0.f, 0.f, 0.f, 0.f};                                     \
        acc = __builtin_amdgcn_mfma_f32_16x16x32_bf16(a0f, bO0, acc, 0, 0, 0);\
        acc = __builtin_amdgcn_mfma_f32_16x16x32_bf16(a1f, bO1, acc, 0, 0, 0);\
        acc = __builtin_amdgcn_mfma_f32_16x16x32_bf16(a2f, bO2, acc, 0, 0, 0);\
        acc = __builtin_amdgcn_mfma_f32_16x16x32_bf16(a3f, bO3, acc, 0, 0, 0);\
        if ((P) < 3) {                                                        \
          bO0 = *(const bf16x8*)(wc2 + (2*(P)+3)*4096 +    0 + lane*16);      \
          bO1 = *(const bf16x8*)(wc2 + (2*(P)+3)*4096 + 1024 + lane*16);      \
          bO2 = *(const bf16x8*)(wc2 + (2*(P)+3)*4096 + 2048 + lane*16);      \
          bO3 = *(const bf16x8*)(wc2 + (2*(P)+3)*4096 + 3072 + lane*16);      \
        }                                                                     \
        uint32_t bsc = bscp[(2*(P)+1)*16];                                    \
        float bc2v = bf2f((short)(bsc & 0xffffu));                            \
        float scv  = bf2f((short)(bsc >> 16));                                \
        ps0 += tanh_fast(acc[0] + bc2v) * scv * bmp[(quad*4+0)*33 + 16 + nl]; \
        ps1 += tanh_fast(acc[1] + bc2v) * scv * bmp[(quad*4+1)*33 + 16 + nl]; \
        ps2 += tanh_fast(acc[2] + bc2v) * scv * bmp[(quad*4+2)*33 + 16 + nl]; \
        ps3 += tanh_fast(acc[3] + bc2v) * scv * bmp[(quad*4+3)*33 + 16 + nl]; \
        ps0 = red16(ps0); ps1 = red16(ps1); ps2 = red16(ps2); ps3 = red16(ps3);\
        if (nl < 4) {                                                         \
          int row = quad * 4 + nl;                                            \
          float s = (nl == 0) ? ps0 : (nl == 1) ? ps1 : (nl == 2) ? ps2 : ps3;\
          ((float*)(lds + LD_Y))[row * 68 + (wv * 4 + (P))] += s;             \
        }                                                                     \
      }

      DIFF_PAIR(0)
      DIFF_PAIR(1)
      DIFF_PAIR(2)
      DIFF_PAIR(3)
#undef DIFF_PAIR
    }
    __syncthreads();   // B3
    // ---- M: vnew = Y(+diff) + DB; rebuild YBF; stage bm/biases ----
    {
      int row = tid >> 6, k = tid & 63;
      float vn = ((float*)(lds + LD_Y))[row * 68 + k] +
                 ((float*)(lds + LD_DB))[row * 68 + k];
      ((float*)(lds + LD_Y))[row * 68 + k] = vn;
      write_act(lds + LD_YBF, row, k, f2bf(vn));
    }
    if (step + 1 < 64) {
      if (tid < 512)
        ((float*)(lds + LD_BM))[(tid >> 5) * 33 + (tid & 31)] = bm_next;
      else if (tid < 768) {
        int j = tid - 512; float v = bbq + (ts0 + (float)(step + 1)) * tvq;
        if (j < 128) ((float*)(lds + LD_BEV))[j] = v;
        else         ((float*)(lds + LD_BEC))[j - 128] = v;
      }
    }
    __syncthreads();   // B4
    // ---- readout: wave wv = row wv; lane = (dd = lane>>3, kchunk = lane&7) --
    {
      int dd = lane >> 3, kg = lane & 7;
      const float* yr = (const float*)(lds + LD_Y) + wv * 68;
      const float* wr = (const float*)(lds + LD_WR) + dd * 68;
      float s = 0.f;
#pragma unroll
      for (int i = 0; i < 8; i++) s = fmaf(yr[kg + 8 * i], wr[kg + 8 * i], s);
      s = red8(s);
      if (kg == 0)
        out[(size_t)(b0 + wv) * 512 + step * 8 + dd] =
            s + ((const float*)(lds + LD_BR))[dd];
    }
  }
}

extern "C" void kernel_launch(void* const* d_in, const int* in_sizes, int n_in,
                              void* d_out, int out_size, void* d_ws, size_t ws_size,
                              hipStream_t stream) {
  (void)in_sizes; (void)n_in; (void)out_size; (void)ws_size;
  const float* ts         = (const float*)d_in[0];
  const float* init_noise = (const float*)d_in[1];
  const float* bm         = (const float*)d_in[2];
  const float* Wi0 = (const float*)d_in[3];
  const float* bi0 = (const float*)d_in[4];
  const float* Wi1 = (const float*)d_in[5];
  const float* bi1 = (const float*)d_in[6];
  const float* Wi2 = (const float*)d_in[7];
  const float* bi2 = (const float*)d_in[8];
  const float* scale_v = (const float*)d_in[9];
  const float* Wv0 = (const float*)d_in[10];
  const float* bv0 = (const float*)d_in[11];
  const float* Wv1 = (const float*)d_in[12];
  const float* bv1 = (const float*)d_in[13];
  const float* Wv2 = (const float*)d_in[14];
  const float* bv2 = (const float*)d_in[15];
  const float* scale_c = (const float*)d_in[16];
  const float* Wc0 = (const float*)d_in[17];
  const float* bc0 = (const float*)d_in[18];
  const float* Wc1 = (const float*)d_in[19];
  const float* bc1 = (const float*)d_in[20];
  const float* Wc2 = (const float*)d_in[21];
  const float* bc2 = (const float*)d_in[22];
  const float* Wr  = (const float*)d_in[23];
  const float* br  = (const float*)d_in[24];
  char*  ws  = (char*)d_ws;
  float* out = (float*)d_out;

  hipFuncSetAttribute((const void*)sde_kernel,
                      hipFuncAttributeMaxDynamicSharedMemorySize, LDS_TOTAL);

  prep_kernel<<<171, 256, 0, stream>>>(Wi0, Wi1, Wi2, Wv0, Wv1, Wv2, Wc0, Wc1, Wc2, ws);
  sde_kernel<<<NWG, 1024, LDS_TOTAL, stream>>>(
      ts, init_noise, bm, bi0, bi1, bi2, bv0, bv1, bv2, scale_v,
      bc0, bc1, bc2, scale_c, Wr, br, ws, out);
}

// Round 11
// 521.254 us; speedup vs baseline: 1.5593x; 1.3942x over previous
//
#include <hip/hip_runtime.h>
#include <stdint.h>
#include <stddef.h>

// ---------------------------------------------------------------------------
// Neural SDE: B=2048 paths, 64 Euler-Maruyama steps.
// R11: consolidation in the proven no-spill regime. 128 self-contained WGs x
// 512 thr (2 waves/SIMD, 256-VGPR budget -- R1/R3 measured zero scratch here;
// every 1024-thr attempt R7-R10 spilled at the 64-arch-VGPR cap). R6 base +:
//  - diffusion: NAMED double-buffered B-frags, 8 macro pairs, all literal
//    indices (R6's rng[sl][k] indexed ring was the last scratch source)
//  - readout balanced over all 8 waves (wave=2 rows, quad-DPP reduce)
//    instead of 2 waves x 64 serial fma
//  - clamp-free 5-op tanh (identical outputs; saturates to +/-1, no NaN)
//  - drift L3 weights in registers (waves 0-3)
// ---------------------------------------------------------------------------

typedef __attribute__((ext_vector_type(8))) short bf16x8;   // 8 x bf16 (4 VGPR)
typedef __attribute__((ext_vector_type(4))) float f32x4;    // MFMA C/D
typedef __attribute__((ext_vector_type(4))) int   i32x4;    // 16B copies

#define BB 16
#define NWG 128

// ---- ws layout (bytes), all bf16 fragment-swizzled weights --------------
#define WS_WI0 0        // 8 frags   (128x32  K=32  KI=1 NT=8)
#define WS_WI1 8192     // 32 frags  (128x128)
#define WS_WI2 40960    // 16 frags  (64x128)
#define WS_WV0 57344    // 16 frags  (128x64, t-col dropped)
#define WS_WV1 73728    // 32 frags
#define WS_WV2 106496   // 16 frags
#define WS_WC0 122880   // 16 frags
#define WS_WC1 139264   // 32 frags
#define WS_WC2 172032   // 512 frags (2048x128) = 512 KB
#define WS_TV0 696320   // Wv0[:,0] f32 [128]
#define WS_TC0 696832   // Wc0[:,0] f32 [128]

// ---- LDS layout (bytes) --------------------------------------------------
#define LD_WV0 0        // 16384
#define LD_WV1 16384    // 32768
#define LD_WC0 49152    // 16384
#define LD_WC1 65536    // 32768
#define LD_YBF 98304    // 2048: y A-frags K=64
#define LD_H1V 100352   // 4096
#define LD_H1C 104448   // 4096
#define LD_H2V 108544   // 4096
#define LD_H2C 112640   // 4096
#define LD_Y   116736   // f32 [16][68] = 4352 (stride 68: 16B-aligned rows)
#define LD_DB  121088   // f32 [16][68]
#define LD_BM  125440   // f32 [16][33] = 2112
#define LD_BSC 127552   // u32 [2048]: bc2(bf16) | scale_c(bf16)<<16 per col
#define LD_BEV 135744   // f32 [128]
#define LD_BEC 136256
#define LD_BV1 136768
#define LD_BC1 137280
#define LD_BV2 137792   // f32 [64]
#define LD_SV  138048
#define LD_WR  138304   // f32 [8][68] = 2176
#define LD_BR  140480   // 32
#define LDS_TOTAL 140512   // >80KB => 1 WG/CU

__device__ __forceinline__ short f2bf(float f) {
  uint32_t u = __builtin_bit_cast(uint32_t, f);
  uint32_t r = (u + 0x7fffu + ((u >> 16) & 1u)) >> 16;   // RNE
  return (short)r;
}
__device__ __forceinline__ float bf2f(short s) {
  uint32_t u = ((uint32_t)(uint16_t)s) << 16;
  return __builtin_bit_cast(float, u);
}
// clamp-free: e->inf => rcp->0 => +1; e->0 => 1-2 = -1. No NaN path.
__device__ __forceinline__ float tanh_fast(float x) {
  float e = __builtin_amdgcn_exp2f(x * 2.8853900817779268f); // 2*log2(e)
  return __builtin_fmaf(-2.f, __builtin_amdgcn_rcpf(e + 1.f), 1.f);
}
__device__ __forceinline__ float lipswish(float x) {
  float s = __builtin_amdgcn_rcpf(1.f + __builtin_amdgcn_exp2f(-1.4426950408889634f * x));
  return 0.909f * x * s;
}
__device__ __forceinline__ float red16(float x) {
  int v;
  v = __builtin_amdgcn_update_dpp(0, __builtin_bit_cast(int, x), 0xB1, 0xF, 0xF, true);
  x += __builtin_bit_cast(float, v);
  v = __builtin_amdgcn_update_dpp(0, __builtin_bit_cast(int, x), 0x4E, 0xF, 0xF, true);
  x += __builtin_bit_cast(float, v);
  v = __builtin_amdgcn_update_dpp(0, __builtin_bit_cast(int, x), 0x141, 0xF, 0xF, true);
  x += __builtin_bit_cast(float, v);
  v = __builtin_amdgcn_update_dpp(0, __builtin_bit_cast(int, x), 0x140, 0xF, 0xF, true);
  x += __builtin_bit_cast(float, v);
  return x;
}
// sum over quad (4 lanes), result in all 4
__device__ __forceinline__ float red4(float x) {
  int v;
  v = __builtin_amdgcn_update_dpp(0, __builtin_bit_cast(int, x), 0xB1, 0xF, 0xF, true);
  x += __builtin_bit_cast(float, v);
  v = __builtin_amdgcn_update_dpp(0, __builtin_bit_cast(int, x), 0x4E, 0xF, 0xF, true);
  x += __builtin_bit_cast(float, v);
  return x;
}
// write activation element (m,k) into a fragment-swizzled bf16 A-buffer
__device__ __forceinline__ void write_act(char* buf, int m, int k, short v) {
  int addr = ((k >> 5) << 10) + (m + ((k >> 3) & 3) * 16) * 16 + ((k & 7) << 1);
  *(short*)(buf + addr) = v;
}

template<int KF>
__device__ __forceinline__ f32x4 gemm_tile(const char* abase, const char* bbase, int lane) {
  f32x4 acc = {0.f, 0.f, 0.f, 0.f};
#pragma unroll
  for (int k = 0; k < KF; k++) {
    bf16x8 a = *(const bf16x8*)(abase + k * 1024 + lane * 16);
    bf16x8 b = *(const bf16x8*)(bbase + k * 1024 + lane * 16);
    acc = __builtin_amdgcn_mfma_f32_16x16x32_bf16(a, b, acc, 0, 0, 0);
  }
  return acc;
}

// ---------------------------------------------------------------------------
// Prep: f32 weights -> bf16 fragment-swizzled blobs in ws. (unchanged)
// ---------------------------------------------------------------------------
__global__ __launch_bounds__(256) void prep_kernel(
    const float* Wi0, const float* Wi1, const float* Wi2,
    const float* Wv0, const float* Wv1, const float* Wv2,
    const float* Wc0, const float* Wc1, const float* Wc2, char* ws) {
  int gid = blockIdx.x * 256 + threadIdx.x;
  if (gid < 680 * 64) {
    int frag = gid >> 6, lane = gid & 63;
    const float* src; int start, KI, srcK, c0;
    if      (frag < 8)   { src = Wi0; start = 0;   KI = 1; srcK = 32;  c0 = 0; }
    else if (frag < 40)  { src = Wi1; start = 8;   KI = 4; srcK = 128; c0 = 0; }
    else if (frag < 56)  { src = Wi2; start = 40;  KI = 4; srcK = 128; c0 = 0; }
    else if (frag < 72)  { src = Wv0; start = 56;  KI = 2; srcK = 65;  c0 = 1; }
    else if (frag < 104) { src = Wv1; start = 72;  KI = 4; srcK = 128; c0 = 0; }
    else if (frag < 120) { src = Wv2; start = 104; KI = 4; srcK = 128; c0 = 0; }
    else if (frag < 136) { src = Wc0; start = 120; KI = 2; srcK = 65;  c0 = 1; }
    else if (frag < 168) { src = Wc1; start = 136; KI = 4; srcK = 128; c0 = 0; }
    else                 { src = Wc2; start = 168; KI = 4; srcK = 128; c0 = 0; }
    int rel = frag - start;
    int nt = rel / KI, ki = rel % KI;
    int n16 = lane & 15, quad = lane >> 4;
    const float* s = src + (nt * 16 + n16) * srcK + c0 + ki * 32 + quad * 8;
    bf16x8 v;
#pragma unroll
    for (int j = 0; j < 8; j++) v[j] = f2bf(s[j]);
    *(bf16x8*)(ws + (size_t)frag * 1024 + lane * 16) = v;
  } else {
    int i = gid - 680 * 64;
    if (i < 128)      ((float*)(ws + WS_TV0))[i] = Wv0[i * 65];
    else if (i < 256) ((float*)(ws + WS_TC0))[i - 128] = Wc0[(i - 128) * 65];
  }
}

// ---------------------------------------------------------------------------
// Main persistent kernel: one WG = 16 batch rows, 8 waves, all 64 steps.
// ---------------------------------------------------------------------------
__global__ __launch_bounds__(512, 2)
void sde_kernel(
    const float* ts, const float* init_noise, const float* bm,
    const float* bi0, const float* bi1, const float* bi2,
    const float* bv0, const float* bv1, const float* bv2, const float* scale_v,
    const float* bc0, const float* bc1, const float* bc2, const float* scale_c,
    const float* Wr, const float* br,
    const char* ws, float* out) {
  extern __shared__ __align__(16) char lds[];
  const int tid  = threadIdx.x;
  const int lane = tid & 63;
  const int wv   = tid >> 6;     // wave 0..7
  const int nl   = lane & 15;
  const int quad = lane >> 4;
  const int b0   = blockIdx.x * BB;
  const char* wc2 = ws + WS_WC2 + (size_t)(wv * 16) * 4096;  // this wave's 16 tiles

  // ---- drift L3 weights in regs (waves 0-3, one-time load) ----
  bf16x8 vf0 = {}, vf1 = {}, vf2 = {}, vf3 = {};
  if (wv < 4) {
    vf0 = *(const bf16x8*)(ws + WS_WV2 + wv * 4096 +    0 + lane * 16);
    vf1 = *(const bf16x8*)(ws + WS_WV2 + wv * 4096 + 1024 + lane * 16);
    vf2 = *(const bf16x8*)(ws + WS_WV2 + wv * 4096 + 2048 + lane * 16);
    vf3 = *(const bf16x8*)(ws + WS_WV2 + wv * 4096 + 3072 + lane * 16);
  }
  // ---- persistent per-thread effective-bias source regs (tids 256..511) ----
  float tvq = 0.f, bbq = 0.f;
  if (tid >= 256) {
    int j = tid - 256;
    if (j < 128) { tvq = ((const float*)(ws + WS_TV0))[j];       bbq = bv0[j]; }
    else         { tvq = ((const float*)(ws + WS_TC0))[j - 128]; bbq = bc0[j - 128]; }
  }

  // ---- stage small weights & params into LDS ----
  {
    const i32x4* s0 = (const i32x4*)(ws + WS_WV0);   // WV0+WV1 = 49152 B
    const i32x4* s1 = (const i32x4*)(ws + WS_WC0);   // WC0+WC1 = 49152 B
    i32x4* d0 = (i32x4*)(lds + LD_WV0);
    i32x4* d1 = (i32x4*)(lds + LD_WC0);
    for (int j = tid; j < 3072; j += 512) { d0[j] = s0[j]; d1[j] = s1[j]; }
  }
  for (int j = tid; j < 2048; j += 512) {   // packed bc2|scale_c per col
    uint32_t u = (uint32_t)(uint16_t)f2bf(bc2[j]) |
                 ((uint32_t)(uint16_t)f2bf(scale_c[j]) << 16);
    ((uint32_t*)(lds + LD_BSC))[j] = u;
  }
  if (tid < 128)      { ((float*)(lds + LD_BV1))[tid] = bv1[tid];
                        ((float*)(lds + LD_BC1))[tid] = bc1[tid]; }
  else if (tid < 192) { int k = tid - 128; ((float*)(lds + LD_BV2))[k] = bv2[k];
                        ((float*)(lds + LD_SV))[k] = scale_v[k]; }
  else if (tid < 200) { int k = tid - 192; ((float*)(lds + LD_BR))[k] = br[k]; }
  { int dd = tid >> 6, k = tid & 63;
    ((float*)(lds + LD_WR))[dd * 68 + k] = Wr[dd * 64 + k]; }
  // init noise -> YBF (K=32)
  { int m = tid >> 5, k = tid & 31;
    write_act(lds + LD_YBF, m, k, f2bf(init_noise[(b0 + m) * 32 + k])); }
  __syncthreads();

  // ---- init MLP: noise -> y0 ----
  { f32x4 acc = gemm_tile<1>(lds + LD_YBF, ws + WS_WI0 + wv * 1024, lane);
    int col = wv * 16 + nl; float bias = bi0[col];
#pragma unroll
    for (int r = 0; r < 4; r++)
      write_act(lds + LD_H1V, quad * 4 + r, col, f2bf(fmaxf(0.f, acc[r] + bias))); }
  __syncthreads();
  { f32x4 acc = gemm_tile<4>(lds + LD_H1V, ws + WS_WI1 + wv * 4096, lane);
    int col = wv * 16 + nl; float bias = bi1[col];
#pragma unroll
    for (int r = 0; r < 4; r++)
      write_act(lds + LD_H2V, quad * 4 + r, col, f2bf(fmaxf(0.f, acc[r] + bias))); }
  __syncthreads();
  if (wv < 4) {
    f32x4 acc = gemm_tile<4>(lds + LD_H2V, ws + WS_WI2 + wv * 4096, lane);
    int col = wv * 16 + nl; float bias = bi2[col];
#pragma unroll
    for (int r = 0; r < 4; r++)
      ((float*)(lds + LD_Y))[(quad * 4 + r) * 68 + col] = acc[r] + bias;
  }
  __syncthreads();

  // ---- preamble: YBF from Y; bm step0; effective biases step0 ----
  const float ts0 = ts[0];
  for (int e = tid; e < 1024; e += 512) {
    int row = e >> 6, k = e & 63;
    write_act(lds + LD_YBF, row, k, f2bf(((float*)(lds + LD_Y))[row * 68 + k]));
  }
  ((float*)(lds + LD_BM))[(tid >> 5) * 33 + (tid & 31)] =
      bm[((size_t)(b0 + (tid >> 5)) * 64 + 0) * 32 + (tid & 31)];
  if (tid >= 256) {
    int j = tid - 256; float v = bbq + ts0 * tvq;
    if (j < 128) ((float*)(lds + LD_BEV))[j] = v;
    else         ((float*)(lds + LD_BEC))[j - 128] = v;
  }
  __syncthreads();

  // ================= 64-step scan =================
  for (int step = 0; step < 64; step++) {
    // ---- step-top prefetch: next bm; B-frag tiles 0,1 (named, held) ----
    float bm_next = 0.f;
    if (step + 1 < 64)
      bm_next = bm[((size_t)(b0 + (tid >> 5)) * 64 + (step + 1)) * 32 + (tid & 31)];
    bf16x8 bE0 = *(const bf16x8*)(wc2 +    0 + lane * 16);
    bf16x8 bE1 = *(const bf16x8*)(wc2 + 1024 + lane * 16);
    bf16x8 bE2 = *(const bf16x8*)(wc2 + 2048 + lane * 16);
    bf16x8 bE3 = *(const bf16x8*)(wc2 + 3072 + lane * 16);
    bf16x8 bO0 = *(const bf16x8*)(wc2 + 4096 +    0 + lane * 16);
    bf16x8 bO1 = *(const bf16x8*)(wc2 + 4096 + 1024 + lane * 16);
    bf16x8 bO2 = *(const bf16x8*)(wc2 + 4096 + 2048 + lane * 16);
    bf16x8 bO3 = *(const bf16x8*)(wc2 + 4096 + 3072 + lane * 16);

    // ---- L1 (each wave: v and c col-tile wv) ----
    {
      int col = wv * 16 + nl;
      f32x4 av = gemm_tile<2>(lds + LD_YBF, lds + LD_WV0 + wv * 2048, lane);
      f32x4 ac = gemm_tile<2>(lds + LD_YBF, lds + LD_WC0 + wv * 2048, lane);
      float bv = ((float*)(lds + LD_BEV))[col];
      float bc = ((float*)(lds + LD_BEC))[col];
#pragma unroll
      for (int r = 0; r < 4; r++) {
        write_act(lds + LD_H1V, quad * 4 + r, col, f2bf(lipswish(av[r] + bv)));
        write_act(lds + LD_H1C, quad * 4 + r, col, f2bf(lipswish(ac[r] + bc)));
      }
    }
    __syncthreads();   // B1
    // ---- L2 ----
    {
      int col = wv * 16 + nl;
      f32x4 av = gemm_tile<4>(lds + LD_H1V, lds + LD_WV1 + wv * 4096, lane);
      f32x4 ac = gemm_tile<4>(lds + LD_H1C, lds + LD_WC1 + wv * 4096, lane);
      float bv = ((float*)(lds + LD_BV1))[col];
      float bc = ((float*)(lds + LD_BC1))[col];
#pragma unroll
      for (int r = 0; r < 4; r++) {
        write_act(lds + LD_H2V, quad * 4 + r, col, f2bf(lipswish(av[r] + bv)));
        write_act(lds + LD_H2C, quad * 4 + r, col, f2bf(lipswish(ac[r] + bc)));
      }
    }
    __syncthreads();   // B2
    // ---- L3: drift (waves 0-3, reg weights) ----
    if (wv < 4) {
      f32x4 acc = {0.f, 0.f, 0.f, 0.f};
      acc = __builtin_amdgcn_mfma_f32_16x16x32_bf16(
          *(const bf16x8*)(lds + LD_H2V +    0 + lane * 16), vf0, acc, 0, 0, 0);
      acc = __builtin_amdgcn_mfma_f32_16x16x32_bf16(
          *(const bf16x8*)(lds + LD_H2V + 1024 + lane * 16), vf1, acc, 0, 0, 0);
      acc = __builtin_amdgcn_mfma_f32_16x16x32_bf16(
          *(const bf16x8*)(lds + LD_H2V + 2048 + lane * 16), vf2, acc, 0, 0, 0);
      acc = __builtin_amdgcn_mfma_f32_16x16x32_bf16(
          *(const bf16x8*)(lds + LD_H2V + 3072 + lane * 16), vf3, acc, 0, 0, 0);
      int col = wv * 16 + nl;
      float bias = ((float*)(lds + LD_BV2))[col];
      float sv   = ((float*)(lds + LD_SV))[col];
#pragma unroll
      for (int r = 0; r < 4; r++)
        ((float*)(lds + LD_DB))[(quad * 4 + r) * 68 + col] = sv * tanh_fast(acc[r] + bias);
    }
    // ---- diffusion: 8 pairs of tiles, named double-buffered B-frags ----
    {
      bf16x8 a0f = *(const bf16x8*)(lds + LD_H2C +    0 + lane * 16);
      bf16x8 a1f = *(const bf16x8*)(lds + LD_H2C + 1024 + lane * 16);
      bf16x8 a2f = *(const bf16x8*)(lds + LD_H2C + 2048 + lane * 16);
      bf16x8 a3f = *(const bf16x8*)(lds + LD_H2C + 3072 + lane * 16);
      const float* bmp = (const float*)(lds + LD_BM);
      float bmr00 = bmp[(quad * 4 + 0) * 33 + nl];
      float bmr01 = bmp[(quad * 4 + 1) * 33 + nl];
      float bmr02 = bmp[(quad * 4 + 2) * 33 + nl];
      float bmr03 = bmp[(quad * 4 + 3) * 33 + nl];
      float bmr10 = bmp[(quad * 4 + 0) * 33 + 16 + nl];
      float bmr11 = bmp[(quad * 4 + 1) * 33 + 16 + nl];
      float bmr12 = bmp[(quad * 4 + 2) * 33 + 16 + nl];
      float bmr13 = bmp[(quad * 4 + 3) * 33 + 16 + nl];
      const uint32_t* bscp = (const uint32_t*)(lds + LD_BSC) + wv * 256 + nl;
      float ps0, ps1, ps2, ps3;

#define DIFF_PAIR(P)                                                          \
      {  /* even tile 2P */                                                   \
        f32x4 acc = {0.f, 0.f, 0.f, 0.f};                                     \
        acc = __builtin_amdgcn_mfma_f32_16x16x32_bf16(a0f, bE0, acc, 0, 0, 0);\
        acc = __builtin_amdgcn_mfma_f32_16x16x32_bf16(a1f, bE1, acc, 0, 0, 0);\
        acc = __builtin_amdgcn_mfma_f32_16x16x32_bf16(a2f, bE2, acc, 0, 0, 0);\
        acc = __builtin_amdgcn_mfma_f32_16x16x32_bf16(a3f, bE3, acc, 0, 0, 0);\
        if ((P) < 7) {                                                        \
          bE0 = *(const bf16x8*)(wc2 + (2*(P)+2)*4096 +    0 + lane*16);      \
          bE1 = *(const bf16x8*)(wc2 + (2*(P)+2)*4096 + 1024 + lane*16);      \
          bE2 = *(const bf16x8*)(wc2 + (2*(P)+2)*4096 + 2048 + lane*16);      \
          bE3 = *(const bf16x8*)(wc2 + (2*(P)+2)*4096 + 3072 + lane*16);      \
        }                                                                     \
        uint32_t bsc = bscp[(2*(P))*16];                                      \
        float bc2v = bf2f((short)(bsc & 0xffffu));                            \
        float scv  = bf2f((short)(bsc >> 16));                                \
        ps0 = tanh_fast(acc[0] + bc2v) * scv * bmr00;                         \
        ps1 = tanh_fast(acc[1] + bc2v) * scv * bmr01;                         \
        ps2 = tanh_fast(acc[2] + bc2v) * scv * bmr02;                         \
        ps3 = tanh_fast(acc[3] + bc2v) * scv * bmr03;                         \
      }                                                                       \
      {  /* odd tile 2P+1 */                                                  \
        f32x4 acc = {0.f, 0.f, 0.f, 0.f};                                     \
        acc = __builtin_amdgcn_mfma_f32_16x16x32_bf16(a0f, bO0, acc, 0, 0, 0);\
        acc = __builtin_amdgcn_mfma_f32_16x16x32_bf16(a1f, bO1, acc, 0, 0, 0);\
        acc = __builtin_amdgcn_mfma_f32_16x16x32_bf16(a2f, bO2, acc, 0, 0, 0);\
        acc = __builtin_amdgcn_mfma_f32_16x16x32_bf16(a3f, bO3, acc, 0, 0, 0);\
        if ((P) < 7) {                                                        \
          bO0 = *(const bf16x8*)(wc2 + (2*(P)+3)*4096 +    0 + lane*16);      \
          bO1 = *(const bf16x8*)(wc2 + (2*(P)+3)*4096 + 1024 + lane*16);      \
          bO2 = *(const bf16x8*)(wc2 + (2*(P)+3)*4096 + 2048 + lane*16);      \
          bO3 = *(const bf16x8*)(wc2 + (2*(P)+3)*4096 + 3072 + lane*16);      \
        }                                                                     \
        uint32_t bsc = bscp[(2*(P)+1)*16];                                    \
        float bc2v = bf2f((short)(bsc & 0xffffu));                            \
        float scv  = bf2f((short)(bsc >> 16));                                \
        ps0 += tanh_fast(acc[0] + bc2v) * scv * bmr10;                        \
        ps1 += tanh_fast(acc[1] + bc2v) * scv * bmr11;                        \
        ps2 += tanh_fast(acc[2] + bc2v) * scv * bmr12;                        \
        ps3 += tanh_fast(acc[3] + bc2v) * scv * bmr13;                        \
        ps0 = red16(ps0); ps1 = red16(ps1); ps2 = red16(ps2); ps3 = red16(ps3);\
        if (nl < 4) {                                                         \
          int row = quad * 4 + nl;                                            \
          float s = (nl == 0) ? ps0 : (nl == 1) ? ps1 : (nl == 2) ? ps2 : ps3;\
          ((float*)(lds + LD_Y))[row * 68 + (wv * 8 + (P))] += s;             \
        }                                                                     \
      }

      DIFF_PAIR(0)
      DIFF_PAIR(1)
      DIFF_PAIR(2)
      DIFF_PAIR(3)
      DIFF_PAIR(4)
      DIFF_PAIR(5)
      DIFF_PAIR(6)
      DIFF_PAIR(7)
#undef DIFF_PAIR
    }
    __syncthreads();   // B3
    // ---- M: vnew = Y(+diff) + DB; rebuild YBF (b64 packed); biases/bm ----
    if (tid < 256) {
      int row = tid >> 4, kb = (tid & 15) * 4;
      f32x4 yv = *(const f32x4*)(lds + LD_Y  + (row * 68 + kb) * 4);
      f32x4 db = *(const f32x4*)(lds + LD_DB + (row * 68 + kb) * 4);
      f32x4 vn = yv + db;
      *(f32x4*)(lds + LD_Y + (row * 68 + kb) * 4) = vn;
      uint32_t p0 = (uint32_t)(uint16_t)f2bf(vn[0]) | ((uint32_t)(uint16_t)f2bf(vn[1]) << 16);
      uint32_t p1 = (uint32_t)(uint16_t)f2bf(vn[2]) | ((uint32_t)(uint16_t)f2bf(vn[3]) << 16);
      uint64_t p64 = (uint64_t)p0 | ((uint64_t)p1 << 32);
      int addr = LD_YBF + ((kb >> 5) << 10) + (row + ((kb >> 3) & 3) * 16) * 16 + ((kb & 7) << 1);
      *(uint64_t*)(lds + addr) = p64;
    } else if (step + 1 < 64) {
      int j = tid - 256; float v = bbq + (ts0 + (float)(step + 1)) * tvq;
      if (j < 128) ((float*)(lds + LD_BEV))[j] = v;
      else         ((float*)(lds + LD_BEC))[j - 128] = v;
    }
    if (step + 1 < 64)
      ((float*)(lds + LD_BM))[(tid >> 5) * 33 + (tid & 31)] = bm_next;
    __syncthreads();   // B4
    // ---- readout: balanced over all 8 waves (wave = 2 rows) ----
    {
      int row = (wv << 1) + (lane >> 5);
      int dd  = (lane >> 2) & 7;
      int kg  = lane & 3;
      const float* yr = (const float*)(lds + LD_Y) + row * 68;
      const float* wr = (const float*)(lds + LD_WR) + dd * 68;
      float s = 0.f;
#pragma unroll
      for (int i = 0; i < 16; i++) s = fmaf(yr[kg + 4 * i], wr[kg + 4 * i], s);
      s = red4(s);
      if (kg == 0)
        out[(size_t)(b0 + row) * 512 + step * 8 + dd] =
            s + ((const float*)(lds + LD_BR))[dd];
    }
  }
}

extern "C" void kernel_launch(void* const* d_in, const int* in_sizes, int n_in,
                              void* d_out, int out_size, void* d_ws, size_t ws_size,
                              hipStream_t stream) {
  (void)in_sizes; (void)n_in; (void)out_size; (void)ws_size;
  const float* ts         = (const float*)d_in[0];
  const float* init_noise = (const float*)d_in[1];
  const float* bm         = (const float*)d_in[2];
  const float* Wi0 = (const float*)d_in[3];
  const float* bi0 = (const float*)d_in[4];
  const float* Wi1 = (const float*)d_in[5];
  const float* bi1 = (const float*)d_in[6];
  const float* Wi2 = (const float*)d_in[7];
  const float* bi2 = (const float*)d_in[8];
  const float* scale_v = (const float*)d_in[9];
  const float* Wv0 = (const float*)d_in[10];
  const float* bv0 = (const float*)d_in[11];
  const float* Wv1 = (const float*)d_in[12];
  const float* bv1 = (const float*)d_in[13];
  const float* Wv2 = (const float*)d_in[14];
  const float* bv2 = (const float*)d_in[15];
  const float* scale_c = (const float*)d_in[16];
  const float* Wc0 = (const float*)d_in[17];
  const float* bc0 = (const float*)d_in[18];
  const float* Wc1 = (const float*)d_in[19];
  const float* bc1 = (const float*)d_in[20];
  const float* Wc2 = (const float*)d_in[21];
  const float* bc2 = (const float*)d_in[22];
  const float* Wr  = (const float*)d_in[23];
  const float* br  = (const float*)d_in[24];
  char*  ws  = (char*)d_ws;
  float* out = (float*)d_out;

  hipFuncSetAttribute((const void*)sde_kernel,
                      hipFuncAttributeMaxDynamicSharedMemorySize, LDS_TOTAL);

  prep_kernel<<<171, 256, 0, stream>>>(Wi0, Wi1, Wi2, Wv0, Wv1, Wv2, Wc0, Wc1, Wc2, ws);
  sde_kernel<<<NWG, 512, LDS_TOTAL, stream>>>(
      ts, init_noise, bm, bi0, bi1, bi2, bv0, bv1, bv2, scale_v,
      bc0, bc1, bc2, scale_c, Wr, br, ws, out);
}